// Round 1
// baseline (479.455 us; speedup 1.0000x reference)
//
#include <hip/hip_runtime.h>
#include <hip/hip_bf16.h>
#include <stdint.h>

// Problem constants (fixed by the reference): B=32, T=4096, Dq=Dk=512, A=512
#define DQ 512
#define DK 512
#define NA 512
#define TT 4096
#define NBATCH 32
#define M_TOTAL (NBATCH * TT)   // 131072 rows of the kp GEMM == out elements

// GEMM tile
#define BM 128
#define BN 128
#define BK 32

typedef __attribute__((ext_vector_type(8))) short bf16x8;   // 8 bf16 = 4 VGPRs (MFMA A/B frag)
typedef __attribute__((ext_vector_type(4))) float f32x4;    // MFMA C/D frag

// async global->LDS, 16B per lane. LDS dst semantics: wave-uniform base + lane*16.
__device__ __forceinline__ void gll16(const void* g, void* l) {
  __builtin_amdgcn_global_load_lds(
      (const __attribute__((address_space(1))) uint32_t*)g,
      (__attribute__((address_space(3))) uint32_t*)l, 16, 0, 0);
}

// fast tanh: 1 - 2/(e^{2x}+1); safe at +/-inf of e (e=inf -> 1, e=0 -> -1)
__device__ __forceinline__ float fast_tanh(float x) {
  float e = __expf(2.0f * x);
  return 1.0f - 2.0f * __builtin_amdgcn_rcpf(e + 1.0f);
}

// --- prep: WkT[a*512+d] = bf16(W[(512+d)*512 + a]); zero out[] (poisoned 0xAA) ---
__global__ void prep_kernel(const float* __restrict__ W,
                            __hip_bfloat16* __restrict__ WkT,
                            float* __restrict__ out) {
  int i = blockIdx.x * 256 + threadIdx.x;   // grid covers 262144
  int d = i & (DK - 1);
  int a = i >> 9;
  WkT[i] = __float2bfloat16(W[(size_t)(DQ + d) * NA + a]);
  if (i < M_TOTAL) out[i] = 0.0f;
}

// --- qpb[b*512+a] = bias[a] + sum_d q[b,d] * W[d*512+a]  (exact fp32) ---
__global__ void qpb_kernel(const float* __restrict__ q,
                           const float* __restrict__ W,
                           const float* __restrict__ bias,
                           float* __restrict__ qpb) {
  int b = blockIdx.x;
  int a = threadIdx.x;          // 512 threads
  const float* qr = q + b * DQ; // wave-uniform -> scalar loads
  float acc = bias[a];
#pragma unroll 16
  for (int d = 0; d < DQ; ++d)
    acc = fmaf(qr[d], W[(size_t)d * NA + a], acc);
  qpb[b * NA + a] = acc;
}

// --- main fused kernel: kp-tile GEMM (bf16 MFMA) + tanh + v-dot + atomic row-sum ---
__global__ __launch_bounds__(256)
void score_kernel(const float* __restrict__ Kmat,          // fp32 [M_TOTAL, DK]
                  const __hip_bfloat16* __restrict__ WkT,  // bf16 [NA, DK]
                  const float* __restrict__ qpb,           // fp32 [NBATCH, NA]
                  const float* __restrict__ v,             // fp32 [NA]
                  float* __restrict__ out) {               // fp32 [M_TOTAL], pre-zeroed
  __shared__ __align__(16) __hip_bfloat16 As[BM * BK];  // [m][k], 64B rows, 8KB
  __shared__ __align__(16) __hip_bfloat16 Bs[BN * BK];  // [n][k], 8KB

  const int tid  = threadIdx.x;
  const int lane = tid & 63;
  const int w    = tid >> 6;   // wave 0..3
  const int wm   = w >> 1;     // 2x2 wave grid, 64x64 per wave
  const int wn   = w & 1;
  const int r16  = lane & 15;
  const int quad = lane >> 4;

  // n_tile in the low bits: the 4 blocks sharing one k M-tile are dispatch-adjacent
  // (different XCDs, shared L3) so k re-reads hit Infinity Cache, not HBM.
  const int n_tile = blockIdx.x & 3;
  const int m_tile = blockIdx.x >> 2;

  const float* Ag = Kmat + (size_t)m_tile * BM * DK;
  const __hip_bfloat16* Bg = WkT + (size_t)n_tile * BN * DK;

  f32x4 acc[4][4];
#pragma unroll
  for (int i = 0; i < 4; ++i)
#pragma unroll
    for (int j = 0; j < 4; ++j) {
      f32x4 z = {0.0f, 0.0f, 0.0f, 0.0f};
      acc[i][j] = z;
    }

  for (int kk = 0; kk < DK; kk += BK) {
    __syncthreads();  // previous iter's frag reads done before overwrite

    // stage B: 8KB bf16 via global_load_lds (2 x 16B per thread)
#pragma unroll
    for (int j = 0; j < 2; ++j) {
      const int s  = j * 256 + tid;           // 16B granule id 0..511
      const int s0 = j * 256 + w * 64;        // wave-uniform base granule
      const __hip_bfloat16* src = Bg + (size_t)(s >> 2) * DK + kk + (s & 3) * 8;
      gll16((const void*)src, (void*)((char*)Bs + (size_t)s0 * 16));
    }

    // stage A: fp32 -> bf16 in regs, 8 contiguous k-elems per chunk, 2 chunks/thread
#pragma unroll
    for (int j = 0; j < 2; ++j) {
      const int c   = j * 256 + tid;          // chunk 0..511
      const int row = c >> 2;
      const int kp  = (c & 3) * 8;
      const float* src = Ag + (size_t)row * DK + kk + kp;
      float4 f0 = *(const float4*)(src);
      float4 f1 = *(const float4*)(src + 4);
      union { bf16x8 v8; __hip_bfloat16 h[8]; } u;
      u.h[0] = __float2bfloat16(f0.x);
      u.h[1] = __float2bfloat16(f0.y);
      u.h[2] = __float2bfloat16(f0.z);
      u.h[3] = __float2bfloat16(f0.w);
      u.h[4] = __float2bfloat16(f1.x);
      u.h[5] = __float2bfloat16(f1.y);
      u.h[6] = __float2bfloat16(f1.z);
      u.h[7] = __float2bfloat16(f1.w);
      *(bf16x8*)(As + row * BK + kp) = u.v8;
    }

    __syncthreads();  // staged data visible (vmcnt+lgkmcnt drained by barrier)

    const bf16x8* Av = (const bf16x8*)As;  // 4 granules per 32-elem row
    const bf16x8* Bv = (const bf16x8*)Bs;
    bf16x8 af[4], bfr[4];
#pragma unroll
    for (int ms = 0; ms < 4; ++ms)
      af[ms] = Av[(wm * 64 + ms * 16 + r16) * 4 + quad];
#pragma unroll
    for (int ns = 0; ns < 4; ++ns)
      bfr[ns] = Bv[(wn * 64 + ns * 16 + r16) * 4 + quad];
#pragma unroll
    for (int ms = 0; ms < 4; ++ms)
#pragma unroll
      for (int ns = 0; ns < 4; ++ns)
        acc[ms][ns] = __builtin_amdgcn_mfma_f32_16x16x32_bf16(
            af[ms], bfr[ns], acc[ms][ns], 0, 0, 0);
  }

  // ---- fused epilogue: tanh(acc + qpb) * v, row-reduce over this block's 128 cols ----
  const size_t row0 = (size_t)m_tile * BM + wm * 64;   // global M row base for this wave
  const int b_idx = (int)(row0 >> 12);                 // 4096 rows per batch, tiles align
  const int a0 = n_tile * BN + wn * 64;

  float vv[4], qv[4];
#pragma unroll
  for (int ns = 0; ns < 4; ++ns) {
    int a = a0 + ns * 16 + r16;   // C/D col = lane&15
    vv[ns] = v[a];
    qv[ns] = qpb[b_idx * NA + a];
  }

#pragma unroll
  for (int ms = 0; ms < 4; ++ms) {
#pragma unroll
    for (int reg = 0; reg < 4; ++reg) {
      float sum = 0.0f;
#pragma unroll
      for (int ns = 0; ns < 4; ++ns) {
        float x = acc[ms][ns][reg] + qv[ns];
        sum = fmaf(fast_tanh(x), vv[ns], sum);
      }
      // C/D row = quad*4+reg; its 16 cols live in lanes quad*16..quad*16+15
      sum += __shfl_xor(sum, 1);
      sum += __shfl_xor(sum, 2);
      sum += __shfl_xor(sum, 4);
      sum += __shfl_xor(sum, 8);
      if (r16 == 0)
        atomicAdd(&out[row0 + ms * 16 + quad * 4 + reg], sum);
    }
  }
}

extern "C" void kernel_launch(void* const* d_in, const int* in_sizes, int n_in,
                              void* d_out, int out_size, void* d_ws, size_t ws_size,
                              hipStream_t stream) {
  const float* q  = (const float*)d_in[0];
  const float* k  = (const float*)d_in[1];
  const float* W  = (const float*)d_in[2];
  const float* b  = (const float*)d_in[3];
  const float* v  = (const float*)d_in[4];
  float* out = (float*)d_out;

  // ws layout: [0,64KB) qpb fp32; [64KB, 64KB+512KB) WkT bf16
  float* qpb = (float*)d_ws;
  __hip_bfloat16* WkT = (__hip_bfloat16*)((char*)d_ws + 65536);

  prep_kernel<<<(NA * DK) / 256, 256, 0, stream>>>(W, WkT, out);
  qpb_kernel<<<NBATCH, NA, 0, stream>>>(q, W, b, qpb);
  score_kernel<<<(M_TOTAL / BM) * (NA / BN), 256, 0, stream>>>(k, WkT, qpb, v, out);
}

// Round 2
// 476.418 us; speedup vs baseline: 1.0064x; 1.0064x over previous
//
#include <hip/hip_runtime.h>
#include <hip/hip_bf16.h>
#include <stdint.h>

// Problem constants: B=32, T=4096, Dq=Dk=512, A=512
#define DQ 512
#define DK 512
#define NA 512
#define TT 4096
#define NBATCH 32
#define M_TOTAL (NBATCH * TT)

// GEMM tile: each block does 64 rows x ALL 512 cols -> no inter-block reduction,
// k (the 256MB input) is fetched exactly once.
#define BM 64
#define BN 512
#define BK 32
#define KITERS (DK / BK)   // 16

typedef __attribute__((ext_vector_type(8))) short bf16x8;   // MFMA A/B frag (4 VGPRs)
typedef __attribute__((ext_vector_type(4))) float f32x4;    // MFMA C/D frag

// async global->LDS, 16B/lane. LDS dst = wave-uniform base + lane*16.
__device__ __forceinline__ void gll16(const void* g, void* l) {
  __builtin_amdgcn_global_load_lds(
      (const __attribute__((address_space(1))) uint32_t*)g,
      (__attribute__((address_space(3))) uint32_t*)l, 16, 0, 0);
}

// fp32 pair -> packed bf16 (round-half-up) in 3 VALU ops: 2 adds + v_perm_b32.
// (vs ~5 insts/elem for __float2bfloat16's RTNE sequence)
__device__ __forceinline__ uint32_t pack2bf16(float a, float b) {
  uint32_t ua = __float_as_uint(a) + 0x8000u;
  uint32_t ub = __float_as_uint(b) + 0x8000u;
  // combined = {ub : ua}; pick bytes 2,3 (ua hi16) then 6,7 (ub hi16)
  return __builtin_amdgcn_perm(ub, ua, 0x07060302);
}

// fast tanh: 1 - 2/(e^{2x}+1); correct limits at +/-inf
__device__ __forceinline__ float fast_tanh(float x) {
  float e = __expf(2.0f * x);
  return 1.0f - 2.0f * __builtin_amdgcn_rcpf(e + 1.0f);
}

// --- prep: WkT[a][d] = bf16(W[512+d][a]) via LDS tile transpose, coalesced both sides ---
__global__ void prep_kernel(const float* __restrict__ W,
                            uint16_t* __restrict__ WkT) {
  __shared__ uint16_t T[64][65];   // +1 pad: odd stride -> conflict-free column reads
  const int tid = threadIdx.x;
  const int d0 = (blockIdx.x & 7) * 64;
  const int a0 = (blockIdx.x >> 3) * 64;
#pragma unroll
  for (int j = 0; j < 16; ++j) {
    int dd = j * 4 + (tid >> 6);
    int aa = tid & 63;                                   // coalesced read (256B/wave)
    uint32_t u = __float_as_uint(W[(size_t)(DQ + d0 + dd) * NA + a0 + aa]) + 0x8000u;
    T[dd][aa] = (uint16_t)(u >> 16);
  }
  __syncthreads();
#pragma unroll
  for (int j = 0; j < 8; ++j) {
    int aa = j * 8 + (tid >> 5);
    int dp = (tid & 31) * 2;                             // dword-coalesced write
    uint32_t val = (uint32_t)T[dp][aa] | ((uint32_t)T[dp + 1][aa] << 16);
    *(uint32_t*)(WkT + (size_t)(a0 + aa) * DK + d0 + dp) = val;
  }
}

// --- qpb[b][a] = bias[a] + q[b]@Wq[:,a], exact fp32. 256 blocks x 1 wave. ---
__global__ void qpb_kernel(const float* __restrict__ q,
                           const float* __restrict__ W,
                           const float* __restrict__ bias,
                           float* __restrict__ qpb) {
  int b = blockIdx.x >> 3;
  int a = (blockIdx.x & 7) * 64 + threadIdx.x;
  const float* qr = q + b * DQ;     // wave-uniform -> scalar/broadcast loads
  float acc = bias[a];
#pragma unroll 8
  for (int d = 0; d < DQ; ++d)
    acc = fmaf(qr[d], W[(size_t)d * NA + a], acc);
  qpb[b * NA + a] = acc;
}

// --- fused: 64x512 kp-tile GEMM (bf16 MFMA) + tanh + v-dot -> direct final store ---
__global__ __launch_bounds__(256, 2)
void score_kernel(const float* __restrict__ Kmat,        // fp32 [M_TOTAL, DK]
                  const uint16_t* __restrict__ WkT,      // bf16 bits [NA, DK]
                  const float* __restrict__ qpb,         // fp32 [NBATCH, NA]
                  const float* __restrict__ v,           // fp32 [NA]
                  float* __restrict__ out) {             // fp32 [M_TOTAL]
  __shared__ __align__(16) uint16_t As[BM * BK];         // 4 KB  [m][k]
  __shared__ __align__(16) uint16_t Bs[BN * BK];         // 32 KB [n][k]
  __shared__ float part[4][BM];                          // 1 KB cross-wave partials

  const int tid  = threadIdx.x;
  const int lane = tid & 63;
  const int w    = tid >> 6;      // wave 0..3 -> col range w*128..w*128+127
  const int r16  = lane & 15;
  const int quad = lane >> 4;
  const int m_tile = blockIdx.x;

  const float* Ag = Kmat + (size_t)m_tile * BM * DK;

  f32x4 acc[4][8];
#pragma unroll
  for (int i = 0; i < 4; ++i)
#pragma unroll
    for (int j = 0; j < 8; ++j) {
      f32x4 z = {0.f, 0.f, 0.f, 0.f};
      acc[i][j] = z;
    }

  // per-thread A staging slot: 8 contiguous k-elems of one row
  const int arow = tid >> 2;
  const int akp  = (tid & 3) * 8;
  const float* Asrc = Ag + (size_t)arow * DK + akp;
  uint16_t* Adst = As + arow * BK + akp;

  for (int it = 0; it < KITERS; ++it) {
    const int kk = it * BK;
    // A global loads issued BEFORE the barrier (overlap prev iter's MFMA tail)
    float4 f0 = *(const float4*)(Asrc + kk);
    float4 f1 = *(const float4*)(Asrc + kk + 4);

    __syncthreads();   // prev iter frag reads complete before LDS overwrite

    // stage B: 32 KB bf16 via global_load_lds (8 x 16B granules per thread)
#pragma unroll
    for (int j = 0; j < 8; ++j) {
      const int g0 = j * 256 + w * 64;          // wave-uniform granule base
      const int g  = g0 + lane;
      const uint16_t* src = WkT + (size_t)(g >> 2) * DK + kk + (g & 3) * 8;
      gll16((const void*)src, (void*)((char*)Bs + (size_t)g0 * 16));
    }

    // stage A: pack fp32->bf16 (12 VALU / 8 elems), one b128 LDS write
    uint4 p;
    p.x = pack2bf16(f0.x, f0.y);
    p.y = pack2bf16(f0.z, f0.w);
    p.z = pack2bf16(f1.x, f1.y);
    p.w = pack2bf16(f1.z, f1.w);
    *(uint4*)Adst = p;

    __syncthreads();   // all staging visible

    const bf16x8* Av = (const bf16x8*)As;   // 4 granules per 32-elem row
    const bf16x8* Bv = (const bf16x8*)Bs;
    bf16x8 af[4], bfr[8];
#pragma unroll
    for (int ms = 0; ms < 4; ++ms)
      af[ms] = Av[(ms * 16 + r16) * 4 + quad];
#pragma unroll
    for (int ns = 0; ns < 8; ++ns)
      bfr[ns] = Bv[(w * 128 + ns * 16 + r16) * 4 + quad];
#pragma unroll
    for (int ms = 0; ms < 4; ++ms)
#pragma unroll
      for (int ns = 0; ns < 8; ++ns)
        acc[ms][ns] = __builtin_amdgcn_mfma_f32_16x16x32_bf16(
            af[ms], bfr[ns], acc[ms][ns], 0, 0, 0);
  }

  // ---- epilogue: tanh(acc + qpb) * v, reduce 512 cols -> 64 row sums, direct store ----
  const size_t row0 = (size_t)m_tile * BM;
  const int b_idx = m_tile >> 6;              // 4096 rows per batch, 64 | 4096

  float vv[8], qv[8];
#pragma unroll
  for (int ns = 0; ns < 8; ++ns) {
    int a = w * 128 + ns * 16 + r16;          // C/D col = lane&15
    vv[ns] = v[a];
    qv[ns] = qpb[b_idx * NA + a];
  }

#pragma unroll
  for (int ms = 0; ms < 4; ++ms) {
#pragma unroll
    for (int reg = 0; reg < 4; ++reg) {
      float s = 0.f;
#pragma unroll
      for (int ns = 0; ns < 8; ++ns) {
        float x = acc[ms][ns][reg] + qv[ns];
        s = fmaf(fast_tanh(x), vv[ns], s);
      }
      // C/D row = quad*4+reg; cols live in the 16 lanes of this quad
      s += __shfl_xor(s, 1);
      s += __shfl_xor(s, 2);
      s += __shfl_xor(s, 4);
      s += __shfl_xor(s, 8);
      if (r16 == 0) part[w][ms * 16 + quad * 4 + reg] = s;
    }
  }
  __syncthreads();
  if (tid < BM)
    out[row0 + tid] = part[0][tid] + part[1][tid] + part[2][tid] + part[3][tid];
}

extern "C" void kernel_launch(void* const* d_in, const int* in_sizes, int n_in,
                              void* d_out, int out_size, void* d_ws, size_t ws_size,
                              hipStream_t stream) {
  const float* q = (const float*)d_in[0];
  const float* k = (const float*)d_in[1];
  const float* W = (const float*)d_in[2];
  const float* b = (const float*)d_in[3];
  const float* v = (const float*)d_in[4];
  float* out = (float*)d_out;

  // ws: [0,64KB) qpb fp32; [64KB,576KB) WkT bf16
  float* qpb = (float*)d_ws;
  uint16_t* WkT = (uint16_t*)((char*)d_ws + 65536);

  prep_kernel<<<64, 256, 0, stream>>>(W, WkT);
  qpb_kernel<<<256, 64, 0, stream>>>(q, W, b, qpb);
  score_kernel<<<M_TOTAL / BM, 256, 0, stream>>>(k, WkT, qpb, v, out);
}

// Round 3
// 447.094 us; speedup vs baseline: 1.0724x; 1.0656x over previous
//
#include <hip/hip_runtime.h>
#include <hip/hip_bf16.h>
#include <stdint.h>

// Problem constants: B=32, T=4096, Dq=Dk=512, A=512
#define DQ 512
#define DK 512
#define NA 512
#define TT 4096
#define NBATCH 32
#define M_TOTAL (NBATCH * TT)

// Block tile: 64 rows x ALL 512 cols (k fetched exactly once, no inter-block
// reduction). 512 threads = 8 waves, each wave 64x64 -> acc only 64 regs/wave
// so 2 blocks/CU (16 waves/CU) fit under __launch_bounds__(512,4).
#define BM 64
#define BK 32
#define KITERS (DK / BK)   // 16

typedef __attribute__((ext_vector_type(8))) short bf16x8;   // MFMA A/B frag (4 VGPRs)
typedef __attribute__((ext_vector_type(4))) float f32x4;    // MFMA C/D frag

// async global->LDS, 16B/lane. LDS dst = wave-uniform base + lane*16.
__device__ __forceinline__ void gll16(const void* g, void* l) {
  __builtin_amdgcn_global_load_lds(
      (const __attribute__((address_space(1))) uint32_t*)g,
      (__attribute__((address_space(3))) uint32_t*)l, 16, 0, 0);
}

// fp32 pair -> packed bf16 (round-half-up): 2 adds + v_perm_b32.
__device__ __forceinline__ uint32_t pack2bf16(float a, float b) {
  uint32_t ua = __float_as_uint(a) + 0x8000u;
  uint32_t ub = __float_as_uint(b) + 0x8000u;
  return __builtin_amdgcn_perm(ub, ua, 0x07060302);   // {ub.hi16 : ua.hi16}
}

// fast tanh: 1 - 2/(e^{2x}+1); correct limits at +/-inf
__device__ __forceinline__ float fast_tanh(float x) {
  float e = __expf(2.0f * x);
  return 1.0f - 2.0f * __builtin_amdgcn_rcpf(e + 1.0f);
}

// --- prep: WkT[a][d] = bf16(W[512+d][a]) via LDS tile transpose ---
__global__ void prep_kernel(const float* __restrict__ W,
                            uint16_t* __restrict__ WkT) {
  __shared__ uint16_t T[64][65];
  const int tid = threadIdx.x;
  const int d0 = (blockIdx.x & 7) * 64;
  const int a0 = (blockIdx.x >> 3) * 64;
#pragma unroll
  for (int j = 0; j < 16; ++j) {
    int dd = j * 4 + (tid >> 6);
    int aa = tid & 63;
    uint32_t u = __float_as_uint(W[(size_t)(DQ + d0 + dd) * NA + a0 + aa]) + 0x8000u;
    T[dd][aa] = (uint16_t)(u >> 16);
  }
  __syncthreads();
#pragma unroll
  for (int j = 0; j < 8; ++j) {
    int aa = j * 8 + (tid >> 5);
    int dp = (tid & 31) * 2;
    uint32_t val = (uint32_t)T[dp][aa] | ((uint32_t)T[dp + 1][aa] << 16);
    *(uint32_t*)(WkT + (size_t)(a0 + aa) * DK + d0 + dp) = val;
  }
}

// --- qpb[b][a] = bias[a] + q[b]@Wq[:,a], exact fp32 ---
__global__ void qpb_kernel(const float* __restrict__ q,
                           const float* __restrict__ W,
                           const float* __restrict__ bias,
                           float* __restrict__ qpb) {
  int b = blockIdx.x >> 3;
  int a = (blockIdx.x & 7) * 64 + threadIdx.x;
  const float* qr = q + b * DQ;
  float acc = bias[a];
#pragma unroll 8
  for (int d = 0; d < DQ; ++d)
    acc = fmaf(qr[d], W[(size_t)d * NA + a], acc);
  qpb[b * NA + a] = acc;
}

// --- fused: 64x512 kp GEMM (bf16 MFMA) + tanh + v-dot -> direct store ---
__global__ __launch_bounds__(512, 4)
void score_kernel(const float* __restrict__ Kmat,        // fp32 [M_TOTAL, DK]
                  const uint16_t* __restrict__ WkT,      // bf16 bits [NA, DK]
                  const float* __restrict__ qpb,         // fp32 [NBATCH, NA]
                  const float* __restrict__ v,           // fp32 [NA]
                  float* __restrict__ out) {             // fp32 [M_TOTAL]
  __shared__ __align__(16) uint16_t As[BM * BK];         // 4 KB  [m][k]
  __shared__ __align__(16) uint16_t Bs[NA * BK];         // 32 KB [n][k]
  __shared__ float part[8][BM];                          // 2 KB cross-wave partials

  const int tid  = threadIdx.x;
  const int lane = tid & 63;
  const int w    = tid >> 6;      // wave 0..7 -> cols w*64 .. w*64+63
  const int r16  = lane & 15;
  const int quad = lane >> 4;
  const int m_tile = blockIdx.x;

  const float* Ag = Kmat + (size_t)m_tile * BM * DK;

  f32x4 acc[4][4];
#pragma unroll
  for (int i = 0; i < 4; ++i)
#pragma unroll
    for (int j = 0; j < 4; ++j) {
      f32x4 z = {0.f, 0.f, 0.f, 0.f};
      acc[i][j] = z;
    }

  // per-thread A slot: 4 contiguous k-elems of one row (512 threads cover 64x32)
  const int arow = tid >> 3;
  const int akp  = (tid & 7) * 4;
  const float* Asrc = Ag + (size_t)arow * DK + akp;
  uint16_t* Adst = As + arow * BK + akp;

  float4 c = *(const float4*)(Asrc);   // preload A(0)

  for (int it = 0; it < KITERS; ++it) {
    const int kk = it * BK;

    __syncthreads();   // (1) prev iter frag reads done; LDS writable

    // stage B(it): 32 KB via global_load_lds, 4 granules/thread
#pragma unroll
    for (int j = 0; j < 4; ++j) {
      const int g0 = j * 512 + w * 64;          // wave-uniform granule base
      const int g  = g0 + lane;
      const uint16_t* src = WkT + (size_t)(g >> 2) * DK + kk + (g & 3) * 8;
      gll16((const void*)src, (void*)((char*)Bs + (size_t)g0 * 16));
    }

    // stage A(it) from prefetched regs: pack fp32->bf16, one b64 LDS write
    uint2 p;
    p.x = pack2bf16(c.x, c.y);
    p.y = pack2bf16(c.z, c.w);
    *(uint2*)Adst = p;

    __syncthreads();   // (2) staging visible

    // prefetch A(it+1) NOW: drains at next iter's barrier (1), covered by
    // the frag-read + MFMA phase below across 16 resident waves/CU.
    if (it + 1 < KITERS) c = *(const float4*)(Asrc + kk + BK);

    const bf16x8* Av = (const bf16x8*)As;   // 4 granules per 32-elem row
    const bf16x8* Bv = (const bf16x8*)Bs;
    bf16x8 af[4], bfr[4];
#pragma unroll
    for (int ms = 0; ms < 4; ++ms)
      af[ms] = Av[(ms * 16 + r16) * 4 + quad];
#pragma unroll
    for (int ns = 0; ns < 4; ++ns)
      bfr[ns] = Bv[(w * 64 + ns * 16 + r16) * 4 + quad];
#pragma unroll
    for (int ms = 0; ms < 4; ++ms)
#pragma unroll
      for (int ns = 0; ns < 4; ++ns)
        acc[ms][ns] = __builtin_amdgcn_mfma_f32_16x16x32_bf16(
            af[ms], bfr[ns], acc[ms][ns], 0, 0, 0);
  }

  // ---- epilogue: tanh(acc + qpb) * v, reduce 512 cols -> 64 row sums ----
  const size_t row0 = (size_t)m_tile * BM;
  const int b_idx = m_tile >> 6;              // 4096 rows/batch, 64 | 4096

  float vv[4], qv[4];
#pragma unroll
  for (int ns = 0; ns < 4; ++ns) {
    int a = w * 64 + ns * 16 + r16;           // C/D col = lane&15
    vv[ns] = v[a];
    qv[ns] = qpb[b_idx * NA + a];
  }

#pragma unroll
  for (int ms = 0; ms < 4; ++ms) {
#pragma unroll
    for (int reg = 0; reg < 4; ++reg) {
      float s = 0.f;
#pragma unroll
      for (int ns = 0; ns < 4; ++ns) {
        float x = acc[ms][ns][reg] + qv[ns];
        s = fmaf(fast_tanh(x), vv[ns], s);
      }
      // C/D row = quad*4+reg; its 16 cols live in this quad's lanes
      s += __shfl_xor(s, 1);
      s += __shfl_xor(s, 2);
      s += __shfl_xor(s, 4);
      s += __shfl_xor(s, 8);
      if (r16 == 0) part[w][ms * 16 + quad * 4 + reg] = s;
    }
  }
  __syncthreads();
  if (tid < BM) {
    float s = 0.f;
#pragma unroll
    for (int ww = 0; ww < 8; ++ww) s += part[ww][tid];
    out[row0 + tid] = s;
  }
}

extern "C" void kernel_launch(void* const* d_in, const int* in_sizes, int n_in,
                              void* d_out, int out_size, void* d_ws, size_t ws_size,
                              hipStream_t stream) {
  const float* q = (const float*)d_in[0];
  const float* k = (const float*)d_in[1];
  const float* W = (const float*)d_in[2];
  const float* b = (const float*)d_in[3];
  const float* v = (const float*)d_in[4];
  float* out = (float*)d_out;

  // ws: [0,64KB) qpb fp32; [64KB,576KB) WkT bf16
  float* qpb = (float*)d_ws;
  uint16_t* WkT = (uint16_t*)((char*)d_ws + 65536);

  prep_kernel<<<64, 256, 0, stream>>>(W, WkT);
  qpb_kernel<<<256, 64, 0, stream>>>(q, W, b, qpb);
  score_kernel<<<M_TOTAL / BM, 512, 0, stream>>>(k, WkT, qpb, v, out);
}

// Round 4
// 436.690 us; speedup vs baseline: 1.0979x; 1.0238x over previous
//
#include <hip/hip_runtime.h>
#include <hip/hip_bf16.h>
#include <stdint.h>

// Problem constants: B=32, T=4096, Dq=Dk=512, A=512
#define DQ 512
#define DK 512
#define NA 512
#define TT 4096
#define NBATCH 32
#define M_TOTAL (NBATCH * TT)

#define BM 64
#define BK 32
#define KITERS (DK / BK)   // 16

typedef __attribute__((ext_vector_type(8))) short bf16x8;   // MFMA A/B frag (4 VGPRs)
typedef __attribute__((ext_vector_type(4))) float f32x4;    // MFMA C/D frag

// async global->LDS, 16B/lane. LDS dst = wave-uniform base + lane*16.
__device__ __forceinline__ void gll16(const void* g, void* l) {
  __builtin_amdgcn_global_load_lds(
      (const __attribute__((address_space(1))) uint32_t*)g,
      (__attribute__((address_space(3))) uint32_t*)l, 16, 0, 0);
}

// fp32 pair -> packed bf16 (round-half-up): 2 adds + v_perm_b32.
__device__ __forceinline__ uint32_t pack2bf16(float a, float b) {
  uint32_t ua = __float_as_uint(a) + 0x8000u;
  uint32_t ub = __float_as_uint(b) + 0x8000u;
  return __builtin_amdgcn_perm(ub, ua, 0x07060302);   // {ub.hi16 : ua.hi16}
}

// fast tanh: 1 - 2/(e^{2x}+1); correct limits at +/-inf
__device__ __forceinline__ float fast_tanh(float x) {
  float e = __expf(2.0f * x);
  return 1.0f - 2.0f * __builtin_amdgcn_rcpf(e + 1.0f);
}

// --- merged prep (W-transpose -> K-blocked tiled bf16) + qpb (exact fp32) ---
// Tiled layout: WkTt[(d>>5)*16384 + n*32 + (d&31)] = bf16(W[512+d][n])
// -> per K-iter the 32KB B panel is contiguous.
__global__ void prep_kernel(const float* __restrict__ W,
                            const float* __restrict__ q,
                            const float* __restrict__ bias,
                            uint16_t* __restrict__ WkTt,
                            float* __restrict__ qpb) {
  const int tid = threadIdx.x;
  if (blockIdx.x < 64) {
    __shared__ uint16_t T[64][65];
    const int d0 = (blockIdx.x & 7) * 64;
    const int a0 = (blockIdx.x >> 3) * 64;
#pragma unroll
    for (int j = 0; j < 16; ++j) {
      int dd = j * 4 + (tid >> 6);
      int aa = tid & 63;   // coalesced read
      uint32_t u = __float_as_uint(W[(size_t)(DQ + d0 + dd) * NA + a0 + aa]) + 0x8000u;
      T[dd][aa] = (uint16_t)(u >> 16);
    }
    __syncthreads();
#pragma unroll
    for (int j = 0; j < 8; ++j) {
      int aa = j * 8 + (tid >> 5);
      int n  = a0 + aa;
      int dp = (tid & 31) * 2;
      int d  = d0 + dp;
      uint32_t val = (uint32_t)T[dp][aa] | ((uint32_t)T[dp + 1][aa] << 16);
      *(uint32_t*)(WkTt + (size_t)(d >> 5) * 16384 + n * 32 + (d & 31)) = val;
    }
  } else {
    const int bb = blockIdx.x - 64;
    const int b  = bb >> 1;
    const int a  = (bb & 1) * 256 + tid;
    const float* qr = q + b * DQ;   // wave-uniform -> scalar loads
    float acc = bias[a];
#pragma unroll 8
    for (int d = 0; d < DQ; ++d)
      acc = fmaf(qr[d], W[(size_t)d * NA + a], acc);
    qpb[b * NA + a] = acc;
  }
}

// --- fused: 64x512 kp GEMM (bf16 MFMA, dbuf LDS, 1 barrier/iter) + tanh + v-dot ---
__global__ __launch_bounds__(512, 4)
void score_kernel(const float* __restrict__ Kmat,        // fp32 [M_TOTAL, DK]
                  const uint16_t* __restrict__ WkTt,     // tiled bf16 [16][512][32]
                  const float* __restrict__ qpb,         // fp32 [NBATCH, NA]
                  const float* __restrict__ v,           // fp32 [NA]
                  float* __restrict__ out) {             // fp32 [M_TOTAL]
  __shared__ __align__(16) uint16_t As[2][BM * BK];      // 2 x 4 KB
  __shared__ __align__(16) uint16_t Bs[2][NA * BK];      // 2 x 32 KB
  __shared__ float part[8][BM];                          // 2 KB

  const int tid  = threadIdx.x;
  const int lane = tid & 63;
  const int w    = tid >> 6;      // wave 0..7 -> cols w*64 .. w*64+63
  const int r16  = lane & 15;
  const int quad = lane >> 4;
  const int m_tile = blockIdx.x;
  // granule swizzle (consistent at write/DMA-src/read): slot = kgran ^ ((row>>1)&3)
  const int sw = quad ^ ((r16 >> 1) & 3);   // frag-read slot, per-lane constant

  const float* Ag = Kmat + (size_t)m_tile * BM * DK;

  f32x4 acc[4][4];
#pragma unroll
  for (int i = 0; i < 4; ++i)
#pragma unroll
    for (int j = 0; j < 4; ++j) {
      f32x4 z = {0.f, 0.f, 0.f, 0.f};
      acc[i][j] = z;
    }

  // ---- B-DMA per-thread source pointers (4 granule-loads/thread/iter) ----
  const uint16_t* bsrc[4];
#pragma unroll
  for (int j = 0; j < 4; ++j) {
    int s   = j * 512 + w * 64 + lane;          // LDS-linear granule id
    int n   = s >> 2;
    int ksl = s & 3;
    int ks  = ksl ^ ((n >> 1) & 3);             // inverse swizzle at source
    bsrc[j] = WkTt + n * 32 + ks * 8;
  }
  const int bdst_off[4] = { (0 * 512 + w * 64) * 16, (1 * 512 + w * 64) * 16,
                            (2 * 512 + w * 64) * 16, (3 * 512 + w * 64) * 16 };

  // ---- A per-thread slot: 4 contiguous k-elems of one row ----
  const int arow = tid >> 3;
  const int akp  = (tid & 7) * 4;
  const float* Asrc = Ag + (size_t)arow * DK + akp;
  const int As_off = arow * 64 + ((akp >> 3) ^ ((arow >> 1) & 3)) * 16 + (akp & 7) * 2;

  // ---- preloop: stage buf0 for it=0; prefetch A(1) ----
#pragma unroll
  for (int j = 0; j < 4; ++j) {
    gll16((const void*)bsrc[j], (void*)((char*)Bs[0] + bdst_off[j]));
    bsrc[j] += 16384;
  }
  {
    float4 c0 = *(const float4*)(Asrc);
    uint2 p;
    p.x = pack2bf16(c0.x, c0.y);
    p.y = pack2bf16(c0.z, c0.w);
    *(uint2*)((char*)As[0] + As_off) = p;
  }
  float4 c = *(const float4*)(Asrc + BK);   // A(1)

#pragma unroll 2
  for (int it = 0; it < KITERS; ++it) {
    const int cur = it & 1, nxt = cur ^ 1;

    __syncthreads();   // drains DMA(it) into buf[cur]; buf[nxt] free for writes

    if (it + 1 < KITERS) {
      // issue B-DMA(it+1) -> buf[nxt]: drains at NEXT barrier, covered by MFMA phase
#pragma unroll
      for (int j = 0; j < 4; ++j) {
        gll16((const void*)bsrc[j], (void*)((char*)Bs[nxt] + bdst_off[j]));
        bsrc[j] += 16384;
      }
      // pack A(it+1) from prefetched regs -> As[nxt]
      uint2 p;
      p.x = pack2bf16(c.x, c.y);
      p.y = pack2bf16(c.z, c.w);
      *(uint2*)((char*)As[nxt] + As_off) = p;
      if (it + 2 < KITERS) c = *(const float4*)(Asrc + (it + 2) * BK);
    }

    // ---- frag reads (swizzled, 2-way max bank aliasing = free) + MFMA ----
    bf16x8 af[4], bfr[4];
#pragma unroll
    for (int ms = 0; ms < 4; ++ms)
      af[ms] = *(const bf16x8*)((char*)As[cur] + (ms * 16 + r16) * 64 + sw * 16);
#pragma unroll
    for (int ns = 0; ns < 4; ++ns)
      bfr[ns] = *(const bf16x8*)((char*)Bs[cur] + (w * 64 + ns * 16 + r16) * 64 + sw * 16);
#pragma unroll
    for (int ms = 0; ms < 4; ++ms)
#pragma unroll
      for (int ns = 0; ns < 4; ++ns)
        acc[ms][ns] = __builtin_amdgcn_mfma_f32_16x16x32_bf16(
            af[ms], bfr[ns], acc[ms][ns], 0, 0, 0);
  }

  // ---- epilogue: tanh(acc + qpb) * v, reduce 512 cols -> 64 row sums ----
  const size_t row0 = (size_t)m_tile * BM;
  const int b_idx = m_tile >> 6;              // 4096 rows/batch, 64 | 4096

  float vv[4], qv[4];
#pragma unroll
  for (int ns = 0; ns < 4; ++ns) {
    int a = w * 64 + ns * 16 + r16;           // C/D col = lane&15
    vv[ns] = v[a];
    qv[ns] = qpb[b_idx * NA + a];
  }

#pragma unroll
  for (int ms = 0; ms < 4; ++ms) {
#pragma unroll
    for (int reg = 0; reg < 4; ++reg) {
      float s = 0.f;
#pragma unroll
      for (int ns = 0; ns < 4; ++ns) {
        float x = acc[ms][ns][reg] + qv[ns];
        s = fmaf(fast_tanh(x), vv[ns], s);
      }
      // C/D row = quad*4+reg; its 16 cols live in this quad's lanes
      s += __shfl_xor(s, 1);
      s += __shfl_xor(s, 2);
      s += __shfl_xor(s, 4);
      s += __shfl_xor(s, 8);
      if (r16 == 0) part[w][ms * 16 + quad * 4 + reg] = s;
    }
  }
  __syncthreads();
  if (tid < BM) {
    float s = 0.f;
#pragma unroll
    for (int ww = 0; ww < 8; ++ww) s += part[ww][tid];
    out[row0 + tid] = s;
  }
}

extern "C" void kernel_launch(void* const* d_in, const int* in_sizes, int n_in,
                              void* d_out, int out_size, void* d_ws, size_t ws_size,
                              hipStream_t stream) {
  const float* q = (const float*)d_in[0];
  const float* k = (const float*)d_in[1];
  const float* W = (const float*)d_in[2];
  const float* b = (const float*)d_in[3];
  const float* v = (const float*)d_in[4];
  float* out = (float*)d_out;

  // ws: [0,64KB) qpb fp32; [64KB,576KB) WkTt bf16 (tiled)
  float* qpb = (float*)d_ws;
  uint16_t* WkTt = (uint16_t*)((char*)d_ws + 65536);

  prep_kernel<<<128, 256, 0, stream>>>(W, q, b, WkTt, qpb);
  score_kernel<<<M_TOTAL / BM, 512, 0, stream>>>(k, WkTt, qpb, v, out);
}